// Round 6
// baseline (2687.870 us; speedup 1.0000x reference)
//
#include <hip/hip_runtime.h>
#include <hip/hip_cooperative_groups.h>

namespace cg = cooperative_groups;

#define NB 1024   // batch
#define TT 32     // encoder length
#define DIN 256   // input dim
#define HD 256    // hidden dim
#define NC 38     // classes
#define NSTEP 26  // decode steps

typedef unsigned short ushort_t;
typedef __attribute__((ext_vector_type(8))) short bf16x8;
typedef __attribute__((ext_vector_type(8))) unsigned short us8;
typedef __attribute__((ext_vector_type(4))) float f32x4;

#define GLOAD_LDS16(g, l) \
  __builtin_amdgcn_global_load_lds((const __attribute__((address_space(1))) unsigned int*)(g), \
                                   (__attribute__((address_space(3))) unsigned int*)(l), 16, 0, 0)

__device__ __forceinline__ unsigned short f2bf(float x) {
    union { float f; unsigned u; } v; v.f = x;
    unsigned r = v.u + 0x7fff + ((v.u >> 16) & 1);   // RNE
    return (unsigned short)(r >> 16);
}
__device__ __forceinline__ float bf2f(unsigned short h) {
    union { unsigned u; float f; } v; v.u = ((unsigned)h) << 16;
    return v.f;
}
__device__ __forceinline__ float fast_tanh(float x) {
    float xc = fminf(fmaxf(x, -15.f), 15.f);
    float z = __expf(2.f * xc);
    return (z - 1.f) * __builtin_amdgcn_rcpf(z + 1.f);
}
__device__ __forceinline__ float fast_sig(float x) {
    return __builtin_amdgcn_rcpf(1.f + __expf(-x));
}

// ---------------------------------------------------------------------------
// prep kernels
// ---------------------------------------------------------------------------
__global__ void prep_B2g(const float* __restrict__ w_ih, const float* __restrict__ w_hh,
                         ushort_t* __restrict__ B2)
{
    int j = blockIdx.x;  // 1024 rows
    for (int k = threadIdx.x; k < 512; k += 256) {
        float x = (k < 256) ? w_ih[(size_t)j * 294 + k] : w_hh[(size_t)j * 256 + (k - 256)];
        unsigned short hi = f2bf(x);
        unsigned short lo = f2bf(x - bf2f(hi));
        size_t r = (size_t)j * 1536;
        B2[r + k] = hi; B2[r + 512 + k] = lo; B2[r + 1024 + k] = hi;
    }
}

__global__ void prep_B2i(const float* __restrict__ w_i2h, ushort_t* __restrict__ B2i)
{
    int n = blockIdx.x;  // 256 rows
    int k = threadIdx.x;
    float x = w_i2h[(size_t)n * 256 + k];
    unsigned short hi = f2bf(x);
    unsigned short lo = f2bf(x - bf2f(hi));
    size_t r = (size_t)n * 768;
    B2i[r + k] = hi; B2i[r + 256 + k] = lo; B2i[r + 512 + k] = hi;
}

__global__ void prep_w2hb(const float* __restrict__ w_h2h, ushort_t* __restrict__ w2hb)
{
    int j = blockIdx.x;
    int d = threadIdx.x;
    w2hb[(size_t)j * 256 + d] = f2bf(w_h2h[(size_t)j * 256 + d]);
}

__global__ __launch_bounds__(256) void prep_encA2(const float* __restrict__ enc,
                                                  ushort_t* __restrict__ encA2)
{
    int base = blockIdx.x * 16;
    int k = threadIdx.x;
#pragma unroll
    for (int rr = 0; rr < 16; rr++) {
        size_t row = base + rr;
        float x = enc[row * 256 + k];
        unsigned short hi = f2bf(x);
        unsigned short lo = f2bf(x - bf2f(hi));
        encA2[row * 512 + k] = hi;
        encA2[row * 512 + 256 + k] = lo;
    }
}

// ---------------------------------------------------------------------------
// hproj_pipe: Hb[m][n] = bf16( sum_k enc[m][k]*w_i2h[n][k] )   (unchanged)
// ---------------------------------------------------------------------------
__global__ __launch_bounds__(256) void hproj_pipe(
    const ushort_t* __restrict__ encA2, const ushort_t* __restrict__ B2i,
    ushort_t* __restrict__ Hb)
{
    __shared__ ushort_t lA[2][64 * 128];
    __shared__ ushort_t lB[2][64 * 128];

    const int tid = threadIdx.x;
    const int lane = tid & 63, wid = tid >> 6;
    const int wm = wid >> 1, wn = wid & 1;
    const int m0 = blockIdx.x * 64, n0 = blockIdx.y * 64;

    f32x4 acc[2][2];
    const f32x4 fz = {0.f, 0.f, 0.f, 0.f};
    acc[0][0] = fz; acc[0][1] = fz; acc[1][0] = fz; acc[1][1] = fz;

    auto stage = [&](int t, int buf) {
#pragma unroll
        for (int i = 0; i < 4; i++) {
            int cpos = tid + i * 256;
            int m = cpos >> 4, p = cpos & 15;
            int g = p ^ (m & 7);
            int vk = t * 128 + g * 8;
            int acol = (vk < 256) ? vk : vk - 256;
            GLOAD_LDS16(&encA2[(size_t)(m0 + m) * 512 + acol], &lA[buf][cpos * 8]);
        }
#pragma unroll
        for (int i = 0; i < 4; i++) {
            int cpos = tid + i * 256;
            int n = cpos >> 4, p = cpos & 15;
            int g = p ^ (n & 7);
            GLOAD_LDS16(&B2i[(size_t)(n0 + n) * 768 + t * 128 + g * 8], &lB[buf][cpos * 8]);
        }
    };

    stage(0, 0);
    stage(1, 1);

    for (int t = 0; t < 6; t++) {
        int cur = t & 1;
        if (t < 5) asm volatile("s_waitcnt vmcnt(8)" ::: "memory");
        else       asm volatile("s_waitcnt vmcnt(0)" ::: "memory");
        __syncthreads();
#pragma unroll
        for (int kk = 0; kk < 4; kk++) {
            int g = kk * 4 + (lane >> 4);
            bf16x8 af[2], bfr[2];
#pragma unroll
            for (int mi = 0; mi < 2; mi++) {
                int m = wm * 32 + mi * 16 + (lane & 15);
                af[mi] = *(const bf16x8*)&lA[cur][m * 128 + ((g ^ (m & 7)) << 3)];
            }
#pragma unroll
            for (int ni = 0; ni < 2; ni++) {
                int n = wn * 32 + ni * 16 + (lane & 15);
                bfr[ni] = *(const bf16x8*)&lB[cur][n * 128 + ((g ^ (n & 7)) << 3)];
            }
#pragma unroll
            for (int mi = 0; mi < 2; mi++)
#pragma unroll
                for (int ni = 0; ni < 2; ni++)
                    acc[mi][ni] = __builtin_amdgcn_mfma_f32_16x16x32_bf16(af[mi], bfr[ni], acc[mi][ni], 0, 0, 0);
        }
        __syncthreads();
        if (t + 2 < 6) stage(t + 2, cur);
    }

    const int r4 = (lane >> 4) * 4;
#pragma unroll
    for (int mi = 0; mi < 2; mi++)
#pragma unroll
        for (int r = 0; r < 4; r++) {
            size_t row = m0 + wm * 32 + mi * 16 + r4 + r;
#pragma unroll
            for (int ni = 0; ni < 2; ni++) {
                int col = n0 + wn * 32 + ni * 16 + (lane & 15);
                Hb[row * 256 + col] = f2bf(acc[mi][ni][r]);
            }
        }
}

// ---------------------------------------------------------------------------
// decode_persist: the whole 26-step loop in one cooperative kernel.
// 256 blocks x 512 threads, 1 block/CU.  Block owns batch rows 4*blk..4*blk+3
// for recur/attention, and gates tile (64*(blk>>4), 64*(blk&15)) for the GEMM.
// h and c live in LDS for the entire kernel.
// ---------------------------------------------------------------------------
__global__ __launch_bounds__(512, 2) void decode_persist(
    const float* __restrict__ enc, const ushort_t* __restrict__ Hb,
    const ushort_t* __restrict__ B2g, const ushort_t* __restrict__ w2hb,
    const float* __restrict__ b_h2h,
    const float* __restrict__ w_gen, const float* __restrict__ b_gen,
    const float* __restrict__ w_score,
    const float* __restrict__ b_ih, const float* __restrict__ b_hh,
    const float* __restrict__ w_ih, const int* __restrict__ text,
    ushort_t* __restrict__ A2, float* __restrict__ gates,
    float* __restrict__ probs)
{
    cg::grid_group grid = cg::this_grid();

    __shared__ ushort_t lA[2][64 * 128];   // 32 KB
    __shared__ ushort_t lB[2][64 * 128];   // 32 KB
    __shared__ float hsh[4][HD];           // 4 KB  (persistent h)
    __shared__ float csh[4][HD];           // 4 KB  (persistent c)
    __shared__ float hpsh[4][HD];          // 4 KB
    __shared__ float esh[4][TT];           // 512 B
    __shared__ float wssh[HD];             // 1 KB

    const int tid = threadIdx.x;
    const int blk = blockIdx.x;
    const int rb0 = blk * 4;               // recur/attn rows
    const int m0 = (blk >> 4) * 64;        // gates tile
    const int n0g = (blk & 15) * 64;
    const int lane = tid & 63, wid = tid >> 6;
    const f32x4 fz = {0.f, 0.f, 0.f, 0.f};

    // ---- prologue: zero h,c and A2 h-parts; load w_score ----
    if (tid < 256) wssh[tid] = w_score[tid];
#pragma unroll
    for (int it = 0; it < 2; it++) {
        int idx = tid + it * 512;
        int bl = idx >> 8, hh = idx & 255;
        hsh[bl][hh] = 0.f;
        csh[bl][hh] = 0.f;
        A2[(size_t)(rb0 + bl) * 1024 + 256 + hh] = 0;
        A2[(size_t)(rb0 + bl) * 1024 + 768 + hh] = 0;
    }
    __syncthreads();

    for (int s = 0; s <= NSTEP; s++) {
        // ---- R phase: LSTM(s-1) + probs(s-1) ----
        if (s > 0) {
            const bool last = (s == NSTEP);
#pragma unroll
            for (int it = 0; it < 2; it++) {
                int idx = tid + it * 512;
                int bl = idx >> 8, hh = idx & 255;
                int b = rb0 + bl;
                const float* g = &gates[(size_t)b * 1024];
                float gi = g[hh];
                float gf = g[256 + hh];
                float gg = g[512 + hh];
                float go = g[768 + hh];
                float cv = csh[bl][hh];
                float cn = fast_sig(gf) * cv + fast_sig(gi) * fast_tanh(gg);
                float hn = fast_sig(go) * fast_tanh(cn);
                csh[bl][hh] = cn;
                hsh[bl][hh] = hn;
                if (!last) {
                    unsigned short hi_ = f2bf(hn);
                    A2[(size_t)b * 1024 + 256 + hh] = hi_;
                    A2[(size_t)b * 1024 + 768 + hh] = f2bf(hn - bf2f(hi_));
                }
            }
            __syncthreads();
            // probs(s-1): 128 threads per row, j<38 active
            {
                int bl = tid >> 7, j = tid & 127;
                if (j < NC) {
                    float acc = b_gen[j];
                    const float* wg = &w_gen[(size_t)j * HD];
                    for (int d = 0; d < HD; d += 4) {
                        float4 wv = *(const float4*)&wg[d];
                        float4 hv = *(const float4*)&hsh[bl][d];
                        acc += wv.x * hv.x + wv.y * hv.y + wv.z * hv.z + wv.w * hv.w;
                    }
                    probs[((size_t)(rb0 + bl) * NSTEP + (s - 1)) * NC + j] = acc;
                }
            }
        }
        if (s == NSTEP) break;

        // ---- hp: hp[b][j] = dot(w_h2h[j] (bf16), h[b]) + b_h2h[j] ----
        {
            int j = tid & 255;
            int hf = tid >> 8;            // handles rows hf*2, hf*2+1
            float a0 = 0.f, a1 = 0.f;
            const ushort_t* wr = &w2hb[(size_t)j * 256];
            for (int d = 0; d < 256; d += 8) {
                us8 wv = *(const us8*)&wr[d];
#pragma unroll
                for (int k = 0; k < 8; k++) {
                    float w = bf2f(wv[k]);
                    a0 += w * hsh[hf * 2 + 0][d + k];
                    a1 += w * hsh[hf * 2 + 1][d + k];
                }
            }
            float bb = b_h2h[j];
            hpsh[hf * 2 + 0][j] = a0 + bb;
            hpsh[hf * 2 + 1][j] = a1 + bb;
        }
        __syncthreads();

        // ---- scores: 4 threads per (bl,t), 64 d each ----
        {
            int pr = tid >> 2, q = tid & 3;
            int bl = pr >> 5, t = pr & 31;
            int d0 = q * 64;
            const ushort_t* hr = &Hb[((size_t)(rb0 + bl) * TT + t) * HD + d0];
            float e = 0.f;
#pragma unroll
            for (int d = 0; d < 64; d += 8) {
                us8 hv = *(const us8*)&hr[d];
#pragma unroll
                for (int k = 0; k < 8; k++) {
                    int dd = d0 + d + k;
                    e += wssh[dd] * fast_tanh(bf2f(hv[k]) + hpsh[bl][dd]);
                }
            }
            e += __shfl_xor(e, 1);
            e += __shfl_xor(e, 2);
            if (q == 0) esh[bl][t] = e;
        }
        __syncthreads();

        // ---- softmax over 32 t, 4 rows on 32-lane groups ----
        if (tid < 128) {
            int bl = tid >> 5, l = tid & 31;
            float v = esh[bl][l];
            float m = v;
#pragma unroll
            for (int o = 16; o > 0; o >>= 1) m = fmaxf(m, __shfl_xor(m, o));
            float p = __expf(v - m);
            float ssum = p;
#pragma unroll
            for (int o = 16; o > 0; o >>= 1) ssum += __shfl_xor(ssum, o);
            esh[bl][l] = p * __builtin_amdgcn_rcpf(ssum);
        }
        __syncthreads();

        // ---- context + A2 ctx hi/lo ----
#pragma unroll
        for (int it = 0; it < 2; it++) {
            int idx = tid + it * 512;
            int bl = idx >> 8, d = idx & 255;
            int b = rb0 + bl;
            const float* er = &enc[(size_t)b * TT * DIN + d];
            float a = 0.f;
#pragma unroll 8
            for (int t = 0; t < TT; t++)
                a += esh[bl][t] * er[(size_t)t * DIN];
            unsigned short hi_ = f2bf(a);
            A2[(size_t)b * 1024 + d] = hi_;
            A2[(size_t)b * 1024 + 512 + d] = f2bf(a - bf2f(hi_));
        }

        grid.sync();

        // ---- G phase: gates tile 64x64, K=1536 virtual ----
        asm volatile("s_waitcnt vmcnt(0)" ::: "memory");
        {
            auto stage = [&](int t, int buf) {
#pragma unroll
                for (int i = 0; i < 2; i++) {
                    int cpos = tid + i * 512;
                    int m = cpos >> 4, p = cpos & 15;
                    int g = p ^ (m & 7);
                    int vk = t * 128 + g * 8;
                    int acol = (vk < 512) ? vk : vk - 512;
                    GLOAD_LDS16(&A2[(size_t)(m0 + m) * 1024 + acol], &lA[buf][cpos * 8]);
                }
#pragma unroll
                for (int i = 0; i < 2; i++) {
                    int cpos = tid + i * 512;
                    int n = cpos >> 4, p = cpos & 15;
                    int g = p ^ (n & 7);
                    GLOAD_LDS16(&B2g[(size_t)(n0g + n) * 1536 + t * 128 + g * 8], &lB[buf][cpos * 8]);
                }
            };

            f32x4 acc[2][2];
            acc[0][0] = fz; acc[0][1] = fz; acc[1][0] = fz; acc[1][1] = fz;
            const int wmg = wid >> 1, wng = wid & 1;   // waves 0-3: 2x2 of 32x32

            stage(0, 0);
            stage(1, 1);

            for (int t = 0; t < 12; t++) {
                int cur = t & 1;
                if (t < 11) asm volatile("s_waitcnt vmcnt(4)" ::: "memory");
                else        asm volatile("s_waitcnt vmcnt(0)" ::: "memory");
                __syncthreads();
                if (wid < 4) {
#pragma unroll
                    for (int kk = 0; kk < 4; kk++) {
                        int g = kk * 4 + (lane >> 4);
                        bf16x8 af[2], bq[2];
#pragma unroll
                        for (int mi = 0; mi < 2; mi++) {
                            int m = wmg * 32 + mi * 16 + (lane & 15);
                            af[mi] = *(const bf16x8*)&lA[cur][m * 128 + ((g ^ (m & 7)) << 3)];
                        }
#pragma unroll
                        for (int ni = 0; ni < 2; ni++) {
                            int n = wng * 32 + ni * 16 + (lane & 15);
                            bq[ni] = *(const bf16x8*)&lB[cur][n * 128 + ((g ^ (n & 7)) << 3)];
                        }
#pragma unroll
                        for (int mi = 0; mi < 2; mi++)
#pragma unroll
                            for (int ni = 0; ni < 2; ni++)
                                acc[mi][ni] = __builtin_amdgcn_mfma_f32_16x16x32_bf16(af[mi], bq[ni], acc[mi][ni], 0, 0, 0);
                    }
                }
                __syncthreads();
                if (t + 2 < 12) stage(t + 2, cur);
            }

            if (wid < 4) {
                const int r4 = (lane >> 4) * 4;
#pragma unroll
                for (int mi = 0; mi < 2; mi++)
#pragma unroll
                    for (int r = 0; r < 4; r++) {
                        int row = m0 + wmg * 32 + mi * 16 + r4 + r;
                        int cl = text[row * NSTEP + s];
#pragma unroll
                        for (int ni = 0; ni < 2; ni++) {
                            int col = n0g + wng * 32 + ni * 16 + (lane & 15);
                            gates[(size_t)row * 1024 + col] =
                                acc[mi][ni][r] + b_ih[col] + b_hh[col]
                                + w_ih[(size_t)col * 294 + 256 + cl];
                        }
                    }
            }
        }

        grid.sync();
    }
}

// ---------------------------------------------------------------------------
extern "C" void kernel_launch(void* const* d_in, const int* in_sizes, int n_in,
                              void* d_out, int out_size, void* d_ws, size_t ws_size,
                              hipStream_t stream)
{
    const float* enc     = (const float*)d_in[0];
    const int*   text    = (const int*)d_in[1];
    const float* w_i2h   = (const float*)d_in[4];
    const float* w_h2h   = (const float*)d_in[5];
    const float* b_h2h   = (const float*)d_in[6];
    const float* w_score = (const float*)d_in[7];
    const float* w_ih    = (const float*)d_in[8];
    const float* w_hh    = (const float*)d_in[9];
    const float* b_ih    = (const float*)d_in[10];
    const float* b_hh    = (const float*)d_in[11];
    const float* w_gen   = (const float*)d_in[12];
    const float* b_gen   = (const float*)d_in[13];
    float* out = (float*)d_out;

    const size_t MB = 1024 * 1024;
    char* ws = (char*)d_ws;
    ushort_t* Hb    = (ushort_t*)ws;                  // 16 MB  [0,16)
    ushort_t* B2g   = (ushort_t*)(ws + 16 * MB);      // 3 MB   [16,19)
    ushort_t* B2i   = (ushort_t*)(ws + 19 * MB);      // 384 KB [19,19.5)
    ushort_t* w2hb  = (ushort_t*)(ws + (size_t)(19.5 * MB)); // 128 KB
    ushort_t* A2    = (ushort_t*)(ws + 20 * MB);      // 2 MB   [20,22)
    float*    gates = (float*)(ws + 22 * MB);         // 4 MB   [22,26)
    ushort_t* encA2 = (ushort_t*)(ws + 26 * MB);      // 32 MB  [26,58)

    prep_B2g<<<1024, 256, 0, stream>>>(w_ih, w_hh, B2g);
    prep_B2i<<<256, 256, 0, stream>>>(w_i2h, B2i);
    prep_w2hb<<<256, 256, 0, stream>>>(w_h2h, w2hb);
    prep_encA2<<<2048, 256, 0, stream>>>(enc, encA2);
    hproj_pipe<<<dim3(512, 4), 256, 0, stream>>>(encA2, B2i, Hb);

    void* kargs[] = {
        (void*)&enc, (void*)&Hb, (void*)&B2g, (void*)&w2hb, (void*)&b_h2h,
        (void*)&w_gen, (void*)&b_gen, (void*)&w_score,
        (void*)&b_ih, (void*)&b_hh, (void*)&w_ih, (void*)&text,
        (void*)&A2, (void*)&gates, (void*)&out
    };
    hipLaunchCooperativeKernel((const void*)decode_persist, dim3(256), dim3(512),
                               kargs, 0, stream);
}

// Round 7
// 1102.007 us; speedup vs baseline: 2.4391x; 2.4391x over previous
//
#include <hip/hip_runtime.h>

#define NB 1024   // batch
#define TT 32     // encoder length
#define DIN 256   // input dim
#define HD 256    // hidden dim
#define NC 38     // classes
#define NSTEP 26  // decode steps

typedef unsigned short ushort_t;
typedef __attribute__((ext_vector_type(8))) short bf16x8;
typedef __attribute__((ext_vector_type(8))) unsigned short us8;
typedef __attribute__((ext_vector_type(4))) float f32x4;

#define GLOAD_LDS16(g, l) \
  __builtin_amdgcn_global_load_lds((const __attribute__((address_space(1))) unsigned int*)(g), \
                                   (__attribute__((address_space(3))) unsigned int*)(l), 16, 0, 0)

__device__ __forceinline__ unsigned short f2bf(float x) {
    union { float f; unsigned u; } v; v.f = x;
    unsigned r = v.u + 0x7fff + ((v.u >> 16) & 1);   // RNE
    return (unsigned short)(r >> 16);
}
__device__ __forceinline__ float bf2f(unsigned short h) {
    union { unsigned u; float f; } v; v.u = ((unsigned)h) << 16;
    return v.f;
}
__device__ __forceinline__ float fast_tanh(float x) {
    float xc = fminf(fmaxf(x, -15.f), 15.f);
    float z = __expf(2.f * xc);
    return (z - 1.f) * __builtin_amdgcn_rcpf(z + 1.f);
}
__device__ __forceinline__ float fast_sig(float x) {
    return __builtin_amdgcn_rcpf(1.f + __expf(-x));
}

// ---------------------------------------------------------------------------
// prep kernels
// ---------------------------------------------------------------------------
__global__ void prep_B2g(const float* __restrict__ w_ih, const float* __restrict__ w_hh,
                         ushort_t* __restrict__ B2)
{
    int j = blockIdx.x;  // 1024 rows
    for (int k = threadIdx.x; k < 512; k += 256) {
        float x = (k < 256) ? w_ih[(size_t)j * 294 + k] : w_hh[(size_t)j * 256 + (k - 256)];
        unsigned short hi = f2bf(x);
        unsigned short lo = f2bf(x - bf2f(hi));
        size_t r = (size_t)j * 1536;
        B2[r + k] = hi; B2[r + 512 + k] = lo; B2[r + 1024 + k] = hi;
    }
}

__global__ void prep_B2i(const float* __restrict__ w_i2h, ushort_t* __restrict__ B2i)
{
    int n = blockIdx.x;  // 256 rows
    int k = threadIdx.x;
    float x = w_i2h[(size_t)n * 256 + k];
    unsigned short hi = f2bf(x);
    unsigned short lo = f2bf(x - bf2f(hi));
    size_t r = (size_t)n * 768;
    B2i[r + k] = hi; B2i[r + 256 + k] = lo; B2i[r + 512 + k] = hi;
}

__global__ void prep_w2hb(const float* __restrict__ w_h2h, ushort_t* __restrict__ w2hb)
{
    int j = blockIdx.x;
    int d = threadIdx.x;
    w2hb[(size_t)j * 256 + d] = f2bf(w_h2h[(size_t)j * 256 + d]);
}

// encA2 row m: [hi(enc) 256 | lo(enc) 256]; encb row m: hi(enc) 256
__global__ __launch_bounds__(256) void prep_encA2b(const float* __restrict__ enc,
                                                   ushort_t* __restrict__ encA2,
                                                   ushort_t* __restrict__ encb)
{
    int base = blockIdx.x * 16;
    int k = threadIdx.x;
#pragma unroll
    for (int rr = 0; rr < 16; rr++) {
        size_t row = base + rr;
        float x = enc[row * 256 + k];
        unsigned short hi = f2bf(x);
        unsigned short lo = f2bf(x - bf2f(hi));
        encA2[row * 512 + k] = hi;
        encA2[row * 512 + 256 + k] = lo;
        encb[row * 256 + k] = hi;
    }
}

// ---------------------------------------------------------------------------
// hproj_pipe: Hb[m][n] = bf16( sum_k enc[m][k]*w_i2h[n][k] )   (unchanged)
// ---------------------------------------------------------------------------
__global__ __launch_bounds__(256) void hproj_pipe(
    const ushort_t* __restrict__ encA2, const ushort_t* __restrict__ B2i,
    ushort_t* __restrict__ Hb)
{
    __shared__ ushort_t lA[2][64 * 128];
    __shared__ ushort_t lB[2][64 * 128];

    const int tid = threadIdx.x;
    const int lane = tid & 63, wid = tid >> 6;
    const int wm = wid >> 1, wn = wid & 1;
    const int m0 = blockIdx.x * 64, n0 = blockIdx.y * 64;

    f32x4 acc[2][2];
    const f32x4 fz = {0.f, 0.f, 0.f, 0.f};
    acc[0][0] = fz; acc[0][1] = fz; acc[1][0] = fz; acc[1][1] = fz;

    auto stage = [&](int t, int buf) {
#pragma unroll
        for (int i = 0; i < 4; i++) {
            int cpos = tid + i * 256;
            int m = cpos >> 4, p = cpos & 15;
            int g = p ^ (m & 7);
            int vk = t * 128 + g * 8;
            int acol = (vk < 256) ? vk : vk - 256;
            GLOAD_LDS16(&encA2[(size_t)(m0 + m) * 512 + acol], &lA[buf][cpos * 8]);
        }
#pragma unroll
        for (int i = 0; i < 4; i++) {
            int cpos = tid + i * 256;
            int n = cpos >> 4, p = cpos & 15;
            int g = p ^ (n & 7);
            GLOAD_LDS16(&B2i[(size_t)(n0 + n) * 768 + t * 128 + g * 8], &lB[buf][cpos * 8]);
        }
    };

    stage(0, 0);
    stage(1, 1);

    for (int t = 0; t < 6; t++) {
        int cur = t & 1;
        if (t < 5) asm volatile("s_waitcnt vmcnt(8)" ::: "memory");
        else       asm volatile("s_waitcnt vmcnt(0)" ::: "memory");
        __syncthreads();
#pragma unroll
        for (int kk = 0; kk < 4; kk++) {
            int g = kk * 4 + (lane >> 4);
            bf16x8 af[2], bfr[2];
#pragma unroll
            for (int mi = 0; mi < 2; mi++) {
                int m = wm * 32 + mi * 16 + (lane & 15);
                af[mi] = *(const bf16x8*)&lA[cur][m * 128 + ((g ^ (m & 7)) << 3)];
            }
#pragma unroll
            for (int ni = 0; ni < 2; ni++) {
                int n = wn * 32 + ni * 16 + (lane & 15);
                bfr[ni] = *(const bf16x8*)&lB[cur][n * 128 + ((g ^ (n & 7)) << 3)];
            }
#pragma unroll
            for (int mi = 0; mi < 2; mi++)
#pragma unroll
                for (int ni = 0; ni < 2; ni++)
                    acc[mi][ni] = __builtin_amdgcn_mfma_f32_16x16x32_bf16(af[mi], bfr[ni], acc[mi][ni], 0, 0, 0);
        }
        __syncthreads();
        if (t + 2 < 6) stage(t + 2, cur);
    }

    const int r4 = (lane >> 4) * 4;
#pragma unroll
    for (int mi = 0; mi < 2; mi++)
#pragma unroll
        for (int r = 0; r < 4; r++) {
            size_t row = m0 + wm * 32 + mi * 16 + r4 + r;
#pragma unroll
            for (int ni = 0; ni < 2; ni++) {
                int col = n0 + wn * 32 + ni * 16 + (lane & 15);
                Hb[row * 256 + col] = f2bf(acc[mi][ni][r]);
            }
        }
}

// ---------------------------------------------------------------------------
// gates_pipe: XCD-pinned 1D grid (256 blocks).
// xcd = bid&7 owns B2g n-panels {2*xcd, 2*xcd+1} (384 KB, L2-resident).
// ---------------------------------------------------------------------------
__global__ __launch_bounds__(256) void gates_pipe(
    const ushort_t* __restrict__ A2, const ushort_t* __restrict__ B2,
    const float* __restrict__ b_ih, const float* __restrict__ b_hh,
    const float* __restrict__ w_ih, const int* __restrict__ text,
    int step, float* __restrict__ gates)
{
    __shared__ ushort_t lA[2][64 * 128];
    __shared__ ushort_t lB[2][64 * 128];

    const int tid = threadIdx.x;
    const int bid = blockIdx.x;
    const int xcd = bid & 7, j = bid >> 3;
    const int m0 = (j >> 1) * 64;
    const int n0 = (xcd * 2 + (j & 1)) * 64;
    const int lane = tid & 63, wid = tid >> 6;
    const int wm = wid >> 1, wn = wid & 1;

    f32x4 acc[2][2];
    const f32x4 fz = {0.f, 0.f, 0.f, 0.f};
    acc[0][0] = fz; acc[0][1] = fz; acc[1][0] = fz; acc[1][1] = fz;

    auto stage = [&](int t, int buf) {
#pragma unroll
        for (int i = 0; i < 4; i++) {
            int cpos = tid + i * 256;
            int m = cpos >> 4, p = cpos & 15;
            int g = p ^ (m & 7);
            int vk = t * 128 + g * 8;
            int acol = (vk < 512) ? vk : vk - 512;
            GLOAD_LDS16(&A2[(size_t)(m0 + m) * 1024 + acol], &lA[buf][cpos * 8]);
        }
#pragma unroll
        for (int i = 0; i < 4; i++) {
            int cpos = tid + i * 256;
            int n = cpos >> 4, p = cpos & 15;
            int g = p ^ (n & 7);
            GLOAD_LDS16(&B2[(size_t)(n0 + n) * 1536 + t * 128 + g * 8], &lB[buf][cpos * 8]);
        }
    };

    stage(0, 0);
    stage(1, 1);

    for (int t = 0; t < 12; t++) {
        int cur = t & 1;
        if (t < 11) asm volatile("s_waitcnt vmcnt(8)" ::: "memory");
        else        asm volatile("s_waitcnt vmcnt(0)" ::: "memory");
        __syncthreads();
#pragma unroll
        for (int kk = 0; kk < 4; kk++) {
            int g = kk * 4 + (lane >> 4);
            bf16x8 af[2], bfr[2];
#pragma unroll
            for (int mi = 0; mi < 2; mi++) {
                int m = wm * 32 + mi * 16 + (lane & 15);
                af[mi] = *(const bf16x8*)&lA[cur][m * 128 + ((g ^ (m & 7)) << 3)];
            }
#pragma unroll
            for (int ni = 0; ni < 2; ni++) {
                int n = wn * 32 + ni * 16 + (lane & 15);
                bfr[ni] = *(const bf16x8*)&lB[cur][n * 128 + ((g ^ (n & 7)) << 3)];
            }
#pragma unroll
            for (int mi = 0; mi < 2; mi++)
#pragma unroll
                for (int ni = 0; ni < 2; ni++)
                    acc[mi][ni] = __builtin_amdgcn_mfma_f32_16x16x32_bf16(af[mi], bfr[ni], acc[mi][ni], 0, 0, 0);
        }
        __syncthreads();
        if (t + 2 < 12) stage(t + 2, cur);
    }

    const int r4 = (lane >> 4) * 4;
#pragma unroll
    for (int mi = 0; mi < 2; mi++)
#pragma unroll
        for (int r = 0; r < 4; r++) {
            int row = m0 + wm * 32 + mi * 16 + r4 + r;
            int cl = text[row * NSTEP + step];
#pragma unroll
            for (int ni = 0; ni < 2; ni++) {
                int col = n0 + wn * 32 + ni * 16 + (lane & 15);
                float v = acc[mi][ni][r] + b_ih[col] + b_hh[col]
                        + w_ih[(size_t)col * 294 + 256 + cl];
                gates[(size_t)row * 1024 + col] = v;
            }
        }
}

// ---------------------------------------------------------------------------
// attn_full: LSTM(s-1) + probs(s-1) + hp + scores + softmax + ctx + A2.
// 1024 blocks x 256 threads, ONE batch row per block, XCD-pinned:
// b = (bid&7)*128 + bid>>3  -> XCD k owns rows [128k,128k+128):
// Hb slice 2 MB + encb slice 2 MB stay L2-resident across all 26 steps.
// ---------------------------------------------------------------------------
__global__ __launch_bounds__(256) void attn_full(
    const float* __restrict__ gates,
    const ushort_t* __restrict__ w2hb, const float* __restrict__ b_h2h,
    const float* __restrict__ w_gen, const float* __restrict__ b_gen,
    const float* __restrict__ w_score,
    const ushort_t* __restrict__ encb, const ushort_t* __restrict__ Hb,
    float* __restrict__ c, ushort_t* __restrict__ A2,
    float* __restrict__ probs, int step)
{
    __shared__ float hsh[HD];
    __shared__ float hpsh[HD];
    __shared__ float wssh[HD];
    __shared__ float esh[TT];
    __shared__ float psh[8][HD + 1];

    const int tid = threadIdx.x;
    const int bid = blockIdx.x;
    const int b = (bid & 7) * 128 + (bid >> 3);

    wssh[tid] = w_score[tid];

    if (step > 0) {
        // LSTM(step-1): one element per thread
        const float* g = &gates[(size_t)b * 1024];
        float gi = g[tid];
        float gf = g[256 + tid];
        float gg = g[512 + tid];
        float go = g[768 + tid];
        float cv = c[(size_t)b * HD + tid];
        float cn = fast_sig(gf) * cv + fast_sig(gi) * fast_tanh(gg);
        float hn = fast_sig(go) * fast_tanh(cn);
        c[(size_t)b * HD + tid] = cn;
        hsh[tid] = hn;
        if (step < NSTEP) {
            unsigned short hi_ = f2bf(hn);
            A2[(size_t)b * 1024 + 256 + tid] = hi_;
            A2[(size_t)b * 1024 + 768 + tid] = f2bf(hn - bf2f(hi_));
        }
        __syncthreads();
        // probs(step-1): 4 threads per class j, 64 d each
        if (tid < 4 * NC) {
            int jj = tid >> 2, q = tid & 3;
            const float* wg = &w_gen[(size_t)jj * HD + q * 64];
            const float* hv = &hsh[q * 64];
            float s = 0.f;
#pragma unroll
            for (int d = 0; d < 64; d += 4) {
                float4 wv = *(const float4*)&wg[d];
                float4 hq = *(const float4*)&hv[d];
                s += wv.x * hq.x + wv.y * hq.y + wv.z * hq.z + wv.w * hq.w;
            }
            s += __shfl_xor(s, 1);
            s += __shfl_xor(s, 2);
            if (q == 0)
                probs[((size_t)b * NSTEP + (step - 1)) * NC + jj] = s + b_gen[jj];
        }
    } else {
        // step 0: h = c = 0
        hsh[tid] = 0.f;
        c[(size_t)b * HD + tid] = 0.f;
        A2[(size_t)b * 1024 + 256 + tid] = 0;
        A2[(size_t)b * 1024 + 768 + tid] = 0;
        __syncthreads();
    }
    if (step >= NSTEP) return;

    // hp[j] = dot(w2hb[j], h) + b_h2h[j], j = tid  (hsh reads broadcast)
    {
        float a = 0.f;
        const ushort_t* wr = &w2hb[(size_t)tid * HD];
#pragma unroll 4
        for (int d = 0; d < HD; d += 8) {
            us8 wv = *(const us8*)&wr[d];
#pragma unroll
            for (int k = 0; k < 8; k++)
                a += bf2f(wv[k]) * hsh[d + k];
        }
        hpsh[tid] = a + b_h2h[tid];
    }
    __syncthreads();

    // scores: 8 threads per t, 32 d each (bf16 Hb)
    {
        int t = tid >> 3, sl = tid & 7;
        const ushort_t* hr = &Hb[((size_t)b * TT + t) * HD];
        float e = 0.f;
#pragma unroll
        for (int jj = 0; jj < 4; jj++) {
            int d0 = sl * 8 + jj * 64;
            us8 hv = *(const us8*)&hr[d0];
#pragma unroll
            for (int k = 0; k < 8; k++) {
                int d = d0 + k;
                e += wssh[d] * fast_tanh(bf2f(hv[k]) + hpsh[d]);
            }
        }
        e += __shfl_xor(e, 4);
        e += __shfl_xor(e, 2);
        e += __shfl_xor(e, 1);
        if (sl == 0) esh[t] = e;
    }
    __syncthreads();

    // softmax over 32 t
    if (tid < 32) {
        float v = esh[tid];
        float m = v;
#pragma unroll
        for (int o = 16; o > 0; o >>= 1) m = fmaxf(m, __shfl_xor(m, o));
        float p = __expf(v - m);
        float ssum = p;
#pragma unroll
        for (int o = 16; o > 0; o >>= 1) ssum += __shfl_xor(ssum, o);
        esh[tid] = p * __builtin_amdgcn_rcpf(ssum);
    }
    __syncthreads();

    // context from bf16 encb: group g=tid>>5 covers t in [4g,4g+4), 8 d/thread
    {
        int g = tid >> 5, l = tid & 31;
        float pp[8] = {0.f, 0.f, 0.f, 0.f, 0.f, 0.f, 0.f, 0.f};
#pragma unroll
        for (int tt = 0; tt < 4; tt++) {
            int t = g * 4 + tt;
            float a = esh[t];
            us8 ev = *(const us8*)&encb[((size_t)b * TT + t) * DIN + l * 8];
#pragma unroll
            for (int k = 0; k < 8; k++)
                pp[k] += a * bf2f(ev[k]);
        }
#pragma unroll
        for (int k = 0; k < 8; k++)
            psh[g][l * 8 + k] = pp[k];
    }
    __syncthreads();
    {
        float a = 0.f;
#pragma unroll
        for (int g = 0; g < 8; g++)
            a += psh[g][tid];
        unsigned short hi_ = f2bf(a);
        A2[(size_t)b * 1024 + tid] = hi_;
        A2[(size_t)b * 1024 + 512 + tid] = f2bf(a - bf2f(hi_));
    }
}

// ---------------------------------------------------------------------------
extern "C" void kernel_launch(void* const* d_in, const int* in_sizes, int n_in,
                              void* d_out, int out_size, void* d_ws, size_t ws_size,
                              hipStream_t stream)
{
    const float* enc     = (const float*)d_in[0];
    const int*   text    = (const int*)d_in[1];
    const float* w_i2h   = (const float*)d_in[4];
    const float* w_h2h   = (const float*)d_in[5];
    const float* b_h2h   = (const float*)d_in[6];
    const float* w_score = (const float*)d_in[7];
    const float* w_ih    = (const float*)d_in[8];
    const float* w_hh    = (const float*)d_in[9];
    const float* b_ih    = (const float*)d_in[10];
    const float* b_hh    = (const float*)d_in[11];
    const float* w_gen   = (const float*)d_in[12];
    const float* b_gen   = (const float*)d_in[13];
    float* out = (float*)d_out;

    const size_t MB = 1024 * 1024;
    char* ws = (char*)d_ws;
    ushort_t* Hb    = (ushort_t*)ws;                  // 16 MB  [0,16)
    ushort_t* B2g   = (ushort_t*)(ws + 16 * MB);      // 3 MB   [16,19)
    ushort_t* B2i   = (ushort_t*)(ws + 19 * MB);      // 384 KB [19,19.5)
    ushort_t* w2hb  = (ushort_t*)(ws + 19 * MB + 512 * 1024); // 128 KB
    float*    cbuf  = (float*)(ws + 20 * MB);         // 1 MB   [20,21)
    ushort_t* A2    = (ushort_t*)(ws + 21 * MB);      // 2 MB   [21,23)
    float*    gates = (float*)(ws + 23 * MB);         // 4 MB   [23,27)
    ushort_t* encA2 = (ushort_t*)(ws + 27 * MB);      // 32 MB  [27,59)
    ushort_t* encb  = (ushort_t*)(ws + 59 * MB);      // 16 MB  [59,75)

    prep_B2g<<<1024, 256, 0, stream>>>(w_ih, w_hh, B2g);
    prep_B2i<<<256, 256, 0, stream>>>(w_i2h, B2i);
    prep_w2hb<<<256, 256, 0, stream>>>(w_h2h, w2hb);
    prep_encA2b<<<2048, 256, 0, stream>>>(enc, encA2, encb);
    hproj_pipe<<<dim3(512, 4), 256, 0, stream>>>(encA2, B2i, Hb);

    for (int s = 0; s < NSTEP; s++) {
        attn_full<<<1024, 256, 0, stream>>>(gates, w2hb, b_h2h, w_gen, b_gen,
                                            w_score, encb, Hb, cbuf, A2, out, s);
        gates_pipe<<<256, 256, 0, stream>>>(A2, B2g, b_ih, b_hh,
                                            w_ih, text, s, gates);
    }
    attn_full<<<1024, 256, 0, stream>>>(gates, w2hb, b_h2h, w_gen, b_gen,
                                        w_score, encb, Hb, cbuf, A2, out, NSTEP);
}